// Round 7
// baseline (257.967 us; speedup 1.0000x reference)
//
#include <hip/hip_runtime.h>
#include <hip/hip_bf16.h>

#define BATCH 4096
#define NTOT  8192
#define DIM   512
#define NTILE 2080   // 64*65/2 upper-triangular 128x128 tiles

typedef __attribute__((ext_vector_type(4))) float floatx4;
typedef __attribute__((ext_vector_type(2))) long longx2;

// ---------------------------------------------------------------- normalize
// One wave per row: read 512 fp32, rsqrt(sum sq), write 512 fp8 e4m3 in the
// k-paired chunk layout simsum wants:
//   row byte g = s*64 + c*16 + h*8 + b  <->  k = 64*s + 32*h + 8*c + b
// so one 16B chunk c of stage s holds [k=64s+8c..+8 | k=64s+32+8c..+8] and a
// single ds_read_b128 yields a lane's fragments for TWO K=32 MFMA steps.
// Blocks 0..31 also zero S; block 0 zeroes the done-counter.
__global__ __launch_bounds__(256) void nrm_kernel(const float* __restrict__ zi,
                                                  const float* __restrict__ zj,
                                                  unsigned char* __restrict__ zq,
                                                  float* __restrict__ S,
                                                  unsigned* __restrict__ done) {
  __shared__ float rb[4][512];
  if (blockIdx.x < 32) S[blockIdx.x * 256 + threadIdx.x] = 0.0f;
  if (blockIdx.x == 0 && threadIdx.x == 0) *done = 0u;
  const int w   = threadIdx.x >> 6;
  const int l   = threadIdx.x & 63;
  const int row = blockIdx.x * 4 + w;
  const float* src = (row < BATCH) ? (zi + (size_t)row * DIM)
                                   : (zj + (size_t)(row - BATCH) * DIM);
  const float4* s4 = (const float4*)src;
  float4 v0 = s4[l];
  float4 v1 = s4[l + 64];
  float ss = v0.x*v0.x + v0.y*v0.y + v0.z*v0.z + v0.w*v0.w
           + v1.x*v1.x + v1.y*v1.y + v1.z*v1.z + v1.w*v1.w;
  #pragma unroll
  for (int m = 1; m < 64; m <<= 1) ss += __shfl_xor(ss, m, 64);
  const float r = 1.0f / fmaxf(sqrtf(ss), 1e-12f);
  rb[w][4*l+0] = v0.x*r; rb[w][4*l+1] = v0.y*r;
  rb[w][4*l+2] = v0.z*r; rb[w][4*l+3] = v0.w*r;
  rb[w][256+4*l+0] = v1.x*r; rb[w][256+4*l+1] = v1.y*r;
  rb[w][256+4*l+2] = v1.z*r; rb[w][256+4*l+3] = v1.w*r;
  __syncthreads();
  // lane l emits row bytes [8l, 8l+8) = k-chunk kc = 8*(l>>3)+4*(l&1)+((l>>1)&3)
  const int kc = 8 * (l >> 3) + 4 * (l & 1) + ((l >> 1) & 3);
  const float* x = &rb[w][kc * 8];
  const int p01 = __builtin_amdgcn_cvt_pk_fp8_f32(x[0], x[1], 0, false);
  const int p23 = __builtin_amdgcn_cvt_pk_fp8_f32(x[2], x[3], 0, false);
  const int p45 = __builtin_amdgcn_cvt_pk_fp8_f32(x[4], x[5], 0, false);
  const int p67 = __builtin_amdgcn_cvt_pk_fp8_f32(x[6], x[7], 0, false);
  uint2 o;
  o.x = (unsigned(p01) & 0xffffu) | (unsigned(p23) << 16);
  o.y = (unsigned(p45) & 0xffffu) | (unsigned(p67) << 16);
  ((uint2*)(zq + (size_t)row * DIM))[l] = o;
}

#define ASYNC16(gp, lp)                                                        \
  __builtin_amdgcn_global_load_lds(                                            \
      (__attribute__((address_space(1))) void*)(gp),                           \
      (__attribute__((address_space(3))) void*)(lp), 16, 0, 0)

// ---------------------------------------------------------------- main GEMM
// fp8 e4m3 Z·Z^T over the 2080 upper-triangular 128x128 tiles (compact grid,
// XCD-swizzled). R3's PROVEN dbuf K-loop (one __syncthreads per iter; raw
// vmcnt tricks regressed in R6). BK=64 stages: LDS/stage = 2x(128x64B)=16KB,
// dbuf 32KB -> 4 blocks/CU. Each ds_read_b128 feeds TWO K=32 MFMA steps
// (k-paired zq layout). XOR swizzle pc = c ^ ((r^(r>>2))&3): 2-way banks.
// Epilogue identical to R3 (verified). Loss fused via last-block ticket.
__global__ __launch_bounds__(256, 4) void simsum_kernel(const unsigned char* __restrict__ zq,
                                                        float* __restrict__ S,
                                                        float* __restrict__ P,
                                                        unsigned* __restrict__ done,
                                                        float* __restrict__ out) {
  // XCD swizzle (XCD ~ blockIdx%8): XCD k owns contiguous tiles [260k,260k+260)
  const int b = blockIdx.x;
  const int u = (b & 7) * 260 + (b >> 3);
  // triangle decode: u = bj*(bj+1)/2 + bi, bi <= bj < 64
  int bj = (int)((sqrtf(8.0f * (float)u + 1.0f) - 1.0f) * 0.5f);
  while ((bj + 1) * (bj + 2) / 2 <= u) ++bj;
  while (bj * (bj + 1) / 2 > u) --bj;
  const int bi = u - bj * (bj + 1) / 2;
  const bool diag = (bi == bj);
  const bool posb = (bj == bi + BATCH / 128);
  const int tileRow = bi * 128;
  const int tileCol = bj * 128;

  __shared__ __align__(16) unsigned char shA[2 * 8192];
  __shared__ __align__(16) unsigned char shB[2 * 8192];
  __shared__ float redR[2][128];
  __shared__ float redC[2][128];

  const int t    = threadIdx.x;
  const int w    = t >> 6;
  const int l    = t & 63;
  const int quad = l >> 4;
  const int lo   = l & 15;
  const int wm   = w >> 1;
  const int wn   = w & 1;

  // staging: wave w stages chunks [w*128, (w+1)*128) of each matrix per stage
  // (two ASYNC16 per matrix). Chunk cid -> LDS byte cid*16 (uniform base +
  // lane*16); holds logical k-chunk c = (cid&3) ^ sw(r), r = cid>>2.
  const int cidA0 = w * 128 + l, cidA1 = cidA0 + 64;
  const int rA0 = cidA0 >> 2, rA1 = cidA1 >> 2;
  const int cA0 = (cidA0 & 3) ^ ((rA0 ^ (rA0 >> 2)) & 3);
  const int cA1 = (cidA1 & 3) ^ ((rA1 ^ (rA1 >> 2)) & 3);
  const unsigned char* gA0 = zq + (size_t)(tileRow + rA0) * DIM + cA0 * 16;
  const unsigned char* gA1 = zq + (size_t)(tileRow + rA1) * DIM + cA1 * 16;
  const unsigned char* gB0 = zq + (size_t)(tileCol + rA0) * DIM + cA0 * 16;
  const unsigned char* gB1 = zq + (size_t)(tileCol + rA1) * DIM + cA1 * 16;
  unsigned char* lA0 = shA + w * 2048;          // chunks w*128..
  unsigned char* lA1 = shA + w * 2048 + 1024;   // chunks w*128+64..
  unsigned char* lB0 = shB + w * 2048;
  unsigned char* lB1 = shB + w * 2048 + 1024;

  floatx4 acc[4][4];
  #pragma unroll
  for (int i = 0; i < 4; ++i)
    #pragma unroll
    for (int j = 0; j < 4; ++j)
      acc[i][j] = (floatx4){0.f, 0.f, 0.f, 0.f};

  // fragment reads: row R = (wm|wn)*64 + i*16 + lo, physical chunk
  // pcRead = quad ^ sw(R); sw(R) = (lo ^ (lo>>2)) & 3 since R%16 == lo.
  const int pcR   = (quad ^ ((lo ^ (lo >> 2)) & 3)) * 16;
  const int aByte = (wm * 64 + lo) * 64 + pcR;  // + i*1024
  const int bByte = (wn * 64 + lo) * 64 + pcR;  // + j*1024

  // prologue: stage 0 into buffer 0
  ASYNC16(gA0, lA0); ASYNC16(gA1, lA1);
  ASYNC16(gB0, lB0); ASYNC16(gB1, lB1);
  gA0 += 64; gA1 += 64; gB0 += 64; gB1 += 64;

  #pragma unroll
  for (int it = 0; it < 8; ++it) {
    __syncthreads();  // drains loads for buffer it&1 (issued one iter ago)
    const int co = (it & 1) * 8192;
    const int no = co ^ 8192;
    if (it < 7) {
      ASYNC16(gA0, lA0 + no); ASYNC16(gA1, lA1 + no);
      ASYNC16(gB0, lB0 + no); ASYNC16(gB1, lB1 + no);
      gA0 += 64; gA1 += 64; gB0 += 64; gB1 += 64;
    }
    longx2 aV[4], bV[4];
    #pragma unroll
    for (int i = 0; i < 4; ++i)
      aV[i] = *(const longx2*)(shA + co + aByte + i * 1024);
    #pragma unroll
    for (int j = 0; j < 4; ++j)
      bV[j] = *(const longx2*)(shB + co + bByte + j * 1024);
    #pragma unroll
    for (int i = 0; i < 4; ++i)
      #pragma unroll
      for (int j = 0; j < 4; ++j)
        acc[i][j] = __builtin_amdgcn_mfma_f32_16x16x32_fp8_fp8(
            aV[i].x, bV[j].x, acc[i][j], 0, 0, 0);
    #pragma unroll
    for (int i = 0; i < 4; ++i)
      #pragma unroll
      for (int j = 0; j < 4; ++j)
        acc[i][j] = __builtin_amdgcn_mfma_f32_16x16x32_fp8_fp8(
            aV[i].y, bV[j].y, acc[i][j], 0, 0, 0);
  }

  // ---- epilogue (identical to R3). C/D: col = lo, row = quad*4 + r
  float rs[4][4];
  float cs[4];
  #pragma unroll
  for (int i = 0; i < 4; ++i)
    #pragma unroll
    for (int r = 0; r < 4; ++r) rs[i][r] = 0.f;
  #pragma unroll
  for (int j = 0; j < 4; ++j) cs[j] = 0.f;

  #pragma unroll
  for (int i = 0; i < 4; ++i)
    #pragma unroll
    for (int j = 0; j < 4; ++j)
      #pragma unroll
      for (int r = 0; r < 4; ++r) {
        const float e = __expf(acc[i][j][r] * 10.0f - 10.0f);
        rs[i][r] += e;
        cs[j] += e;
      }

  // block-local diagonal lanes: wm==wn, lo == quad*4 + r (quad == lo>>2)
  if (wm == wn && quad == (lo >> 2)) {
    const int r = lo & 3;
    if (diag) {  // remove self-similarity from row & col sums
      #pragma unroll
      for (int i = 0; i < 4; ++i) {
        const float e = __expf(acc[i][i][r] * 10.0f - 10.0f);
        rs[i][r] -= e;
        cs[i] -= e;
      }
    }
    if (posb) {  // positives: col == row + BATCH
      #pragma unroll
      for (int i = 0; i < 4; ++i) {
        const int row = tileRow + wm * 64 + i * 16 + lo;
        const float v = acc[i][i][r] * 10.0f;
        P[row] = v;
        P[row + BATCH] = v;
      }
    }
  }

  // row sums: reduce across 16 column-lanes (low 4 lane bits)
  #pragma unroll
  for (int m = 1; m < 16; m <<= 1) {
    #pragma unroll
    for (int i = 0; i < 4; ++i)
      #pragma unroll
      for (int r = 0; r < 4; ++r)
        rs[i][r] += __shfl_xor(rs[i][r], m, 64);
  }
  if (lo == 0) {
    #pragma unroll
    for (int i = 0; i < 4; ++i)
      #pragma unroll
      for (int r = 0; r < 4; ++r)
        redR[wn][wm * 64 + i * 16 + quad * 4 + r] = rs[i][r];
  }
  // col sums: reduce across the 4 quads (lane bits 4,5)
  #pragma unroll
  for (int m = 16; m < 64; m <<= 1) {
    #pragma unroll
    for (int j = 0; j < 4; ++j) cs[j] += __shfl_xor(cs[j], m, 64);
  }
  if (quad == 0) {
    #pragma unroll
    for (int j = 0; j < 4; ++j)
      redC[wm][wn * 64 + j * 16 + lo] = cs[j];
  }
  __syncthreads();
  if (t < 128) {
    atomicAdd(&S[tileRow + t], redR[0][t] + redR[1][t]);
  } else if (!diag) {
    const int c = t - 128;
    atomicAdd(&S[tileCol + c], redC[0][c] + redC[1][c]);
  }

  // ---- last-block loss reduction (proven R5/R6)
  __threadfence();                       // release S/P updates (device scope)
  __shared__ unsigned ticket;
  if (t == 0) ticket = atomicAdd(done, 1u);
  __syncthreads();
  if (ticket == NTILE - 1) {
    __threadfence();                     // acquire all other blocks' S/P
    float acc2 = 0.f;
    for (int i = t; i < NTOT; i += 256)
      acc2 += 10.0f + logf(S[i]) - P[i];
    #pragma unroll
    for (int m = 1; m < 64; m <<= 1) acc2 += __shfl_xor(acc2, m, 64);
    __shared__ float sb[4];
    if (l == 0) sb[w] = acc2;
    __syncthreads();
    if (t == 0)
      out[0] = (sb[0] + sb[1] + sb[2] + sb[3]) * (1.0f / (float)NTOT);
  }
}

extern "C" void kernel_launch(void* const* d_in, const int* in_sizes, int n_in,
                              void* d_out, int out_size, void* d_ws, size_t ws_size,
                              hipStream_t stream) {
  const float* zi = (const float*)d_in[0];
  const float* zj = (const float*)d_in[1];
  unsigned char* zq = (unsigned char*)d_ws;                      // 4 MB fp8
  float*    S    = (float*)((char*)d_ws + (size_t)NTOT * DIM);   // 32 KB
  float*    P    = S + NTOT;                                     // 32 KB
  unsigned* done = (unsigned*)(P + NTOT);                        // 4 B
  float*    out  = (float*)d_out;

  nrm_kernel<<<NTOT / 4, 256, 0, stream>>>(zi, zj, zq, S, done);
  simsum_kernel<<<NTILE, 256, 0, stream>>>(zq, S, P, done, out);
}

// Round 8
// 220.644 us; speedup vs baseline: 1.1692x; 1.1692x over previous
//
#include <hip/hip_runtime.h>
#include <hip/hip_bf16.h>

#define BATCH 4096
#define NTOT  8192
#define DIM   512
#define NTILE 2080   // 64*65/2 upper-triangular 128x128 tiles

typedef __attribute__((ext_vector_type(4))) float floatx4;
typedef __attribute__((ext_vector_type(2))) long longx2;

// ---------------------------------------------------------------- normalize
// One wave per row: read 512 fp32, rsqrt(sum sq), write 512 fp8 e4m3 in the
// k-paired chunk layout simsum wants:
//   row byte g = s*64 + c*16 + h*8 + b  <->  k = 64*s + 32*h + 8*c + b
// so one 16B chunk c of stage s holds [k=64s+8c..+8 | k=64s+32+8c..+8] and a
// single ds_read_b128 yields a lane's fragments for TWO K=32 MFMA steps.
// Blocks 0..31 also zero S; block 0 zeroes the done-counter.
__global__ __launch_bounds__(256) void nrm_kernel(const float* __restrict__ zi,
                                                  const float* __restrict__ zj,
                                                  unsigned char* __restrict__ zq,
                                                  float* __restrict__ S,
                                                  unsigned* __restrict__ done) {
  __shared__ float rb[4][512];
  if (blockIdx.x < 32) S[blockIdx.x * 256 + threadIdx.x] = 0.0f;
  if (blockIdx.x == 0 && threadIdx.x == 0) *done = 0u;
  const int w   = threadIdx.x >> 6;
  const int l   = threadIdx.x & 63;
  const int row = blockIdx.x * 4 + w;
  const float* src = (row < BATCH) ? (zi + (size_t)row * DIM)
                                   : (zj + (size_t)(row - BATCH) * DIM);
  const float4* s4 = (const float4*)src;
  float4 v0 = s4[l];
  float4 v1 = s4[l + 64];
  float ss = v0.x*v0.x + v0.y*v0.y + v0.z*v0.z + v0.w*v0.w
           + v1.x*v1.x + v1.y*v1.y + v1.z*v1.z + v1.w*v1.w;
  #pragma unroll
  for (int m = 1; m < 64; m <<= 1) ss += __shfl_xor(ss, m, 64);
  const float r = 1.0f / fmaxf(sqrtf(ss), 1e-12f);
  rb[w][4*l+0] = v0.x*r; rb[w][4*l+1] = v0.y*r;
  rb[w][4*l+2] = v0.z*r; rb[w][4*l+3] = v0.w*r;
  rb[w][256+4*l+0] = v1.x*r; rb[w][256+4*l+1] = v1.y*r;
  rb[w][256+4*l+2] = v1.z*r; rb[w][256+4*l+3] = v1.w*r;
  __syncthreads();
  // lane l emits row bytes [8l, 8l+8) = k-chunk kc = 8*(l>>3)+4*(l&1)+((l>>1)&3)
  const int kc = 8 * (l >> 3) + 4 * (l & 1) + ((l >> 1) & 3);
  const float* x = &rb[w][kc * 8];
  const int p01 = __builtin_amdgcn_cvt_pk_fp8_f32(x[0], x[1], 0, false);
  const int p23 = __builtin_amdgcn_cvt_pk_fp8_f32(x[2], x[3], 0, false);
  const int p45 = __builtin_amdgcn_cvt_pk_fp8_f32(x[4], x[5], 0, false);
  const int p67 = __builtin_amdgcn_cvt_pk_fp8_f32(x[6], x[7], 0, false);
  uint2 o;
  o.x = (unsigned(p01) & 0xffffu) | (unsigned(p23) << 16);
  o.y = (unsigned(p45) & 0xffffu) | (unsigned(p67) << 16);
  ((uint2*)(zq + (size_t)row * DIM))[l] = o;
}

#define ASYNC16(gp, lp)                                                        \
  __builtin_amdgcn_global_load_lds(                                            \
      (__attribute__((address_space(1))) void*)(gp),                           \
      (__attribute__((address_space(3))) void*)(lp), 16, 0, 0)

// ---------------------------------------------------------------- main GEMM
// fp8 e4m3 Z·Z^T over the 2080 upper-triangular 128x128 tiles (compact grid,
// XCD-swizzled). R3's PROVEN dbuf K-loop (one __syncthreads per iter).
// BK=64 stages: LDS/stage = 16KB, dbuf 32KB. Each ds_read_b128 feeds TWO
// K=32 MFMA steps (k-paired zq layout). NO min-waves launch bound: R7's
// (256,4) capped the unified VGPR+AGPR file at 128 -> 40B/thread scratch
// spills (WRITE_SIZE 20.9 MB) -> 200us. Unified file needs ~148 regs.
// Epilogue identical to R3 (verified). Loss fused via last-block ticket.
__global__ __launch_bounds__(256) void simsum_kernel(const unsigned char* __restrict__ zq,
                                                     float* __restrict__ S,
                                                     float* __restrict__ P,
                                                     unsigned* __restrict__ done,
                                                     float* __restrict__ out) {
  // XCD swizzle (XCD ~ blockIdx%8): XCD k owns contiguous tiles [260k,260k+260)
  const int b = blockIdx.x;
  const int u = (b & 7) * 260 + (b >> 3);
  // triangle decode: u = bj*(bj+1)/2 + bi, bi <= bj < 64
  int bj = (int)((sqrtf(8.0f * (float)u + 1.0f) - 1.0f) * 0.5f);
  while ((bj + 1) * (bj + 2) / 2 <= u) ++bj;
  while (bj * (bj + 1) / 2 > u) --bj;
  const int bi = u - bj * (bj + 1) / 2;
  const bool diag = (bi == bj);
  const bool posb = (bj == bi + BATCH / 128);
  const int tileRow = bi * 128;
  const int tileCol = bj * 128;

  __shared__ __align__(16) unsigned char shA[2 * 8192];
  __shared__ __align__(16) unsigned char shB[2 * 8192];
  __shared__ float redR[2][128];
  __shared__ float redC[2][128];

  const int t    = threadIdx.x;
  const int w    = t >> 6;
  const int l    = t & 63;
  const int quad = l >> 4;
  const int lo   = l & 15;
  const int wm   = w >> 1;
  const int wn   = w & 1;

  // staging: wave w stages chunks [w*128, (w+1)*128) of each matrix per stage
  // (two ASYNC16 per matrix). Chunk cid -> LDS byte cid*16 (uniform base +
  // lane*16); holds logical k-chunk c = (cid&3) ^ sw(r), r = cid>>2.
  const int cidA0 = w * 128 + l, cidA1 = cidA0 + 64;
  const int rA0 = cidA0 >> 2, rA1 = cidA1 >> 2;
  const int cA0 = (cidA0 & 3) ^ ((rA0 ^ (rA0 >> 2)) & 3);
  const int cA1 = (cidA1 & 3) ^ ((rA1 ^ (rA1 >> 2)) & 3);
  const unsigned char* gA0 = zq + (size_t)(tileRow + rA0) * DIM + cA0 * 16;
  const unsigned char* gA1 = zq + (size_t)(tileRow + rA1) * DIM + cA1 * 16;
  const unsigned char* gB0 = zq + (size_t)(tileCol + rA0) * DIM + cA0 * 16;
  const unsigned char* gB1 = zq + (size_t)(tileCol + rA1) * DIM + cA1 * 16;
  unsigned char* lA0 = shA + w * 2048;          // chunks w*128..
  unsigned char* lA1 = shA + w * 2048 + 1024;   // chunks w*128+64..
  unsigned char* lB0 = shB + w * 2048;
  unsigned char* lB1 = shB + w * 2048 + 1024;

  floatx4 acc[4][4];
  #pragma unroll
  for (int i = 0; i < 4; ++i)
    #pragma unroll
    for (int j = 0; j < 4; ++j)
      acc[i][j] = (floatx4){0.f, 0.f, 0.f, 0.f};

  // fragment reads: row R = (wm|wn)*64 + i*16 + lo, physical chunk
  // pcRead = quad ^ sw(R); sw(R) = (lo ^ (lo>>2)) & 3 since R%16 == lo.
  const int pcR   = (quad ^ ((lo ^ (lo >> 2)) & 3)) * 16;
  const int aByte = (wm * 64 + lo) * 64 + pcR;  // + i*1024
  const int bByte = (wn * 64 + lo) * 64 + pcR;  // + j*1024

  // prologue: stage 0 into buffer 0
  ASYNC16(gA0, lA0); ASYNC16(gA1, lA1);
  ASYNC16(gB0, lB0); ASYNC16(gB1, lB1);
  gA0 += 64; gA1 += 64; gB0 += 64; gB1 += 64;

  #pragma unroll
  for (int it = 0; it < 8; ++it) {
    __syncthreads();  // drains loads for buffer it&1 (issued one iter ago)
    const int co = (it & 1) * 8192;
    const int no = co ^ 8192;
    if (it < 7) {
      ASYNC16(gA0, lA0 + no); ASYNC16(gA1, lA1 + no);
      ASYNC16(gB0, lB0 + no); ASYNC16(gB1, lB1 + no);
      gA0 += 64; gA1 += 64; gB0 += 64; gB1 += 64;
    }
    longx2 aV[4], bV[4];
    #pragma unroll
    for (int i = 0; i < 4; ++i)
      aV[i] = *(const longx2*)(shA + co + aByte + i * 1024);
    #pragma unroll
    for (int j = 0; j < 4; ++j)
      bV[j] = *(const longx2*)(shB + co + bByte + j * 1024);
    #pragma unroll
    for (int i = 0; i < 4; ++i)
      #pragma unroll
      for (int j = 0; j < 4; ++j)
        acc[i][j] = __builtin_amdgcn_mfma_f32_16x16x32_fp8_fp8(
            aV[i].x, bV[j].x, acc[i][j], 0, 0, 0);
    #pragma unroll
    for (int i = 0; i < 4; ++i)
      #pragma unroll
      for (int j = 0; j < 4; ++j)
        acc[i][j] = __builtin_amdgcn_mfma_f32_16x16x32_fp8_fp8(
            aV[i].y, bV[j].y, acc[i][j], 0, 0, 0);
  }

  // ---- epilogue (identical to R3). C/D: col = lo, row = quad*4 + r
  float rs[4][4];
  float cs[4];
  #pragma unroll
  for (int i = 0; i < 4; ++i)
    #pragma unroll
    for (int r = 0; r < 4; ++r) rs[i][r] = 0.f;
  #pragma unroll
  for (int j = 0; j < 4; ++j) cs[j] = 0.f;

  #pragma unroll
  for (int i = 0; i < 4; ++i)
    #pragma unroll
    for (int j = 0; j < 4; ++j)
      #pragma unroll
      for (int r = 0; r < 4; ++r) {
        const float e = __expf(acc[i][j][r] * 10.0f - 10.0f);
        rs[i][r] += e;
        cs[j] += e;
      }

  // block-local diagonal lanes: wm==wn, lo == quad*4 + r (quad == lo>>2)
  if (wm == wn && quad == (lo >> 2)) {
    const int r = lo & 3;
    if (diag) {  // remove self-similarity from row & col sums
      #pragma unroll
      for (int i = 0; i < 4; ++i) {
        const float e = __expf(acc[i][i][r] * 10.0f - 10.0f);
        rs[i][r] -= e;
        cs[i] -= e;
      }
    }
    if (posb) {  // positives: col == row + BATCH
      #pragma unroll
      for (int i = 0; i < 4; ++i) {
        const int row = tileRow + wm * 64 + i * 16 + lo;
        const float v = acc[i][i][r] * 10.0f;
        P[row] = v;
        P[row + BATCH] = v;
      }
    }
  }

  // row sums: reduce across 16 column-lanes (low 4 lane bits)
  #pragma unroll
  for (int m = 1; m < 16; m <<= 1) {
    #pragma unroll
    for (int i = 0; i < 4; ++i)
      #pragma unroll
      for (int r = 0; r < 4; ++r)
        rs[i][r] += __shfl_xor(rs[i][r], m, 64);
  }
  if (lo == 0) {
    #pragma unroll
    for (int i = 0; i < 4; ++i)
      #pragma unroll
      for (int r = 0; r < 4; ++r)
        redR[wn][wm * 64 + i * 16 + quad * 4 + r] = rs[i][r];
  }
  // col sums: reduce across the 4 quads (lane bits 4,5)
  #pragma unroll
  for (int m = 16; m < 64; m <<= 1) {
    #pragma unroll
    for (int j = 0; j < 4; ++j) cs[j] += __shfl_xor(cs[j], m, 64);
  }
  if (quad == 0) {
    #pragma unroll
    for (int j = 0; j < 4; ++j)
      redC[wm][wn * 64 + j * 16 + lo] = cs[j];
  }
  __syncthreads();
  if (t < 128) {
    atomicAdd(&S[tileRow + t], redR[0][t] + redR[1][t]);
  } else if (!diag) {
    const int c = t - 128;
    atomicAdd(&S[tileCol + c], redC[0][c] + redC[1][c]);
  }

  // ---- last-block loss reduction (proven R5/R6)
  __threadfence();                       // release S/P updates (device scope)
  __shared__ unsigned ticket;
  if (t == 0) ticket = atomicAdd(done, 1u);
  __syncthreads();
  if (ticket == NTILE - 1) {
    __threadfence();                     // acquire all other blocks' S/P
    float acc2 = 0.f;
    for (int i = t; i < NTOT; i += 256)
      acc2 += 10.0f + logf(S[i]) - P[i];
    #pragma unroll
    for (int m = 1; m < 64; m <<= 1) acc2 += __shfl_xor(acc2, m, 64);
    __shared__ float sb[4];
    if (l == 0) sb[w] = acc2;
    __syncthreads();
    if (t == 0)
      out[0] = (sb[0] + sb[1] + sb[2] + sb[3]) * (1.0f / (float)NTOT);
  }
}

extern "C" void kernel_launch(void* const* d_in, const int* in_sizes, int n_in,
                              void* d_out, int out_size, void* d_ws, size_t ws_size,
                              hipStream_t stream) {
  const float* zi = (const float*)d_in[0];
  const float* zj = (const float*)d_in[1];
  unsigned char* zq = (unsigned char*)d_ws;                      // 4 MB fp8
  float*    S    = (float*)((char*)d_ws + (size_t)NTOT * DIM);   // 32 KB
  float*    P    = S + NTOT;                                     // 32 KB
  unsigned* done = (unsigned*)(P + NTOT);                        // 4 B
  float*    out  = (float*)d_out;

  nrm_kernel<<<NTOT / 4, 256, 0, stream>>>(zi, zj, zq, S, done);
  simsum_kernel<<<NTILE, 256, 0, stream>>>(zq, S, P, done, out);
}